// Round 1
// baseline (572.355 us; speedup 1.0000x reference)
//
#include <hip/hip_runtime.h>
#include <stdint.h>

#define T_SEQ   2048
#define HID     4096
#define NH      32
#define NKV     8
#define HD      128
#define QCOLS   6144
#define QK_SCALE 0.08838834764831845f  // 1/sqrt(128)

typedef _Float16 half_t;
typedef _Float16 half8 __attribute__((ext_vector_type(8)));
typedef _Float16 half4v __attribute__((ext_vector_type(4)));
typedef float    f32x4 __attribute__((ext_vector_type(4)));

typedef __attribute__((address_space(1))) const void cg_void;
typedef __attribute__((address_space(3))) void lds_void;

// ---------------- cast fp32 -> fp16 (vectorized) ----------------
__global__ __launch_bounds__(256) void cast_f32_f16_k(const float* __restrict__ in,
                                                      half_t* __restrict__ out, int n4) {
  int i = blockIdx.x * 256 + threadIdx.x;
  if (i >= n4) return;
  f32x4 v = *(const f32x4*)(in + (size_t)i * 4);
  half4v o;
  o[0] = (half_t)v[0]; o[1] = (half_t)v[1]; o[2] = (half_t)v[2]; o[3] = (half_t)v[3];
  *(half4v*)(out + (size_t)i * 4) = o;
}

// ---------------- RoPE cos/sin tables ----------------
__global__ __launch_bounds__(256) void rope_tables_k(float* __restrict__ cs) {
  int idx = blockIdx.x * 256 + threadIdx.x;  // 2048*64
  int t = idx >> 6, i = idx & 63;
  // inv_freq = 10000^(-i/64) = exp(-i * ln(10000)/64)
  float inv = expf(-(float)i * 0.14391156831212787f);
  float a = (float)t * inv;
  cs[idx] = cosf(a);
  cs[131072 + idx] = sinf(a);
}

// ---------------- RoPE apply (in-place on fp16 QKV buffer) ----------------
// heads 0..31 = Q (also fold QK_SCALE), heads 32..39 = K. V untouched.
__global__ __launch_bounds__(256) void rope_apply_k(half_t* __restrict__ QKV,
                                                    const float* __restrict__ cs) {
  int idx = blockIdx.x * 256 + threadIdx.x;  // 2048*40*64
  int i = idx & 63;
  int rem = idx >> 6;          // t*40 + head
  int head = rem % 40;
  int t = rem / 40;
  int colbase = (head < 32) ? head * HD : HID + (head - 32) * HD;
  size_t base = (size_t)t * QCOLS + colbase;
  float c = cs[t * 64 + i], s = cs[131072 + t * 64 + i];
  float x1 = (float)QKV[base + i];
  float x2 = (float)QKV[base + 64 + i];
  float o1 = x1 * c - x2 * s;
  float o2 = x1 * s + x2 * c;
  if (head < 32) { o1 *= QK_SCALE; o2 *= QK_SCALE; }
  QKV[base + i]      = (half_t)o1;
  QKV[base + 64 + i] = (half_t)o2;
}

// ---------------- fp16 GEMM: C[M][N] = A[M][K] * B[N][K]^T ----------------
// 128x128 tile, BK=64, 4 waves (2x2), global_load_lds w/ pre-swizzled source,
// XOR-swizzled ds_read_b128 (2-way conflicts).
template <int OUT_HALF>
__global__ __launch_bounds__(256) void gemm_bt(const half_t* __restrict__ A,
                                               const half_t* __restrict__ B,
                                               void* __restrict__ Cout,
                                               int M, int N, int K) {
  __shared__ half_t Alds[128 * 64];
  __shared__ half_t Blds[128 * 64];
  const int row0 = blockIdx.x * 128;
  const int col0 = blockIdx.y * 128;
  const int tid  = threadIdx.x;
  const int lane = tid & 63;
  const int wid  = tid >> 6;
  const int wr = wid >> 1, wc = wid & 1;
  const int lr = lane & 15, hi = lane >> 4;

  f32x4 acc[4][4] = {};

  for (int k0 = 0; k0 < K; k0 += 64) {
#pragma unroll
    for (int c = 0; c < 4; ++c) {
      int idx = c * 256 + tid;        // 16B-slot index 0..1023
      int r = idx >> 3, s = idx & 7;
      int cc = s ^ (r & 7);           // pre-swizzled source chunk
      int base = (c * 256 + wid * 64) * 8;  // wave-uniform LDS element base
      __builtin_amdgcn_global_load_lds(
          (cg_void*)(A + (size_t)(row0 + r) * K + k0 + cc * 8),
          (lds_void*)(&Alds[base]), 16, 0, 0);
      __builtin_amdgcn_global_load_lds(
          (cg_void*)(B + (size_t)(col0 + r) * K + k0 + cc * 8),
          (lds_void*)(&Blds[base]), 16, 0, 0);
    }
    __syncthreads();
#pragma unroll
    for (int kk = 0; kk < 2; ++kk) {
      half8 af[4], bf[4];
#pragma unroll
      for (int mi = 0; mi < 4; ++mi) {
        int ra = wr * 64 + mi * 16 + lr;
        int slot = (kk * 4 + hi) ^ (ra & 7);
        af[mi] = *(const half8*)&Alds[ra * 64 + slot * 8];
      }
#pragma unroll
      for (int ni = 0; ni < 4; ++ni) {
        int rb = wc * 64 + ni * 16 + lr;
        int slot = (kk * 4 + hi) ^ (rb & 7);
        bf[ni] = *(const half8*)&Blds[rb * 64 + slot * 8];
      }
#pragma unroll
      for (int mi = 0; mi < 4; ++mi)
#pragma unroll
        for (int ni = 0; ni < 4; ++ni)
          acc[mi][ni] = __builtin_amdgcn_mfma_f32_16x16x32_f16(af[mi], bf[ni], acc[mi][ni], 0, 0, 0);
    }
    __syncthreads();
  }

#pragma unroll
  for (int mi = 0; mi < 4; ++mi)
#pragma unroll
    for (int ni = 0; ni < 4; ++ni)
#pragma unroll
      for (int r = 0; r < 4; ++r) {
        int row = row0 + wr * 64 + mi * 16 + hi * 4 + r;
        int col = col0 + wc * 64 + ni * 16 + lr;
        float v = acc[mi][ni][r];
        if (OUT_HALF) ((half_t*)Cout)[(size_t)row * N + col] = (half_t)v;
        else          ((float*)Cout)[(size_t)row * N + col] = v;
      }
}

// ---------------- fused causal GQA flash attention ----------------
// grid (32 qblocks x 32 heads), 256 thr = 4 waves; wave w owns q rows
// [qb*64 + w*16, +16). KV tiles of 32. fp16 MFMA 16x16x32, fp32 online softmax.
__global__ __launch_bounds__(256) void attn_k(const half_t* __restrict__ QKV,
                                              half_t* __restrict__ Ob) {
  const int qb = blockIdx.x;
  const int h  = blockIdx.y;
  const int kh = h >> 2;
  const int tid = threadIdx.x;
  const int lane = tid & 63;
  const int w = tid >> 6;
  const int lr = lane & 15, hi = lane >> 4;
  const int q0 = qb * 64;
  const int qrow = q0 + w * 16;

  __shared__ half_t Klds[32 * 128];   // swizzled-linear (global_load_lds)
  __shared__ half_t Vlds[32 * 136];   // padded row-major
  __shared__ half_t Plds[4 * 16 * 32];

  const half_t* Qp = QKV + h * HD;
  const half_t* Kp = QKV + HID + kh * HD;
  const half_t* Vp = QKV + HID + NKV * HD + kh * HD;

  half8 qf[4];
#pragma unroll
  for (int kk = 0; kk < 4; ++kk)
    qf[kk] = *(const half8*)&Qp[(size_t)(qrow + lr) * QCOLS + kk * 32 + hi * 8];

  f32x4 acc[8] = {};
  float mrow[4], lrow[4];
#pragma unroll
  for (int r = 0; r < 4; ++r) { mrow[r] = -1e30f; lrow[r] = 0.0f; }

  const int nt = 2 * qb + 2;
  for (int t = 0; t < nt; ++t) {
    const int kv0 = t * 32;
    // ---- stage K (global_load_lds, swizzled source) + V (reg-staged) ----
#pragma unroll
    for (int call = 0; call < 2; ++call) {
      int chunk = call * 256 + tid;     // 0..511
      int r = chunk >> 4, c = chunk & 15;
      int cc = (c & 8) | ((c ^ r) & 7);
      __builtin_amdgcn_global_load_lds(
          (cg_void*)(Kp + (size_t)(kv0 + r) * QCOLS + cc * 8),
          (lds_void*)(&Klds[(call * 256 + w * 64) * 8]), 16, 0, 0);
      half8 vv = *(const half8*)&Vp[(size_t)(kv0 + r) * QCOLS + c * 8];
      *(half8*)&Vlds[r * 136 + c * 8] = vv;
    }
    __syncthreads();

    // ---- S = Q K^T (16 rows x 32 cols) ----
    f32x4 s[2] = {};
#pragma unroll
    for (int jt = 0; jt < 2; ++jt)
#pragma unroll
      for (int kk = 0; kk < 4; ++kk) {
        int m = kk * 4 + hi;
        int cslot = (m & 8) | ((m ^ lr) & 7);
        half8 kf = *(const half8*)&Klds[(jt * 16 + lr) * 128 + cslot * 8];
        s[jt] = __builtin_amdgcn_mfma_f32_16x16x32_f16(qf[kk], kf, s[jt], 0, 0, 0);
      }

    // ---- causal mask ----
    if (kv0 + 31 > qrow) {
#pragma unroll
      for (int jt = 0; jt < 2; ++jt)
#pragma unroll
        for (int r = 0; r < 4; ++r) {
          int ig = qrow + hi * 4 + r;
          int jg = kv0 + jt * 16 + lr;
          if (jg > ig) s[jt][r] = -1e30f;
        }
    }

    // ---- online softmax (rows spread over 16-lane groups) ----
    float mx[4], scl[4], ls[4];
#pragma unroll
    for (int r = 0; r < 4; ++r) mx[r] = fmaxf(s[0][r], s[1][r]);
#pragma unroll
    for (int off = 1; off < 16; off <<= 1)
#pragma unroll
      for (int r = 0; r < 4; ++r)
        mx[r] = fmaxf(mx[r], __shfl_xor(mx[r], off, 64));
#pragma unroll
    for (int r = 0; r < 4; ++r) {
      float mn = fmaxf(mrow[r], mx[r]);
      scl[r] = __expf(mrow[r] - mn);
      mrow[r] = mn;
      s[0][r] = __expf(s[0][r] - mn);
      s[1][r] = __expf(s[1][r] - mn);
      ls[r] = s[0][r] + s[1][r];
    }
#pragma unroll
    for (int off = 1; off < 16; off <<= 1)
#pragma unroll
      for (int r = 0; r < 4; ++r)
        ls[r] += __shfl_xor(ls[r], off, 64);
#pragma unroll
    for (int r = 0; r < 4; ++r) lrow[r] = lrow[r] * scl[r] + ls[r];
#pragma unroll
    for (int g = 0; g < 8; ++g)
#pragma unroll
      for (int r = 0; r < 4; ++r) acc[g][r] *= scl[r];

    // ---- P -> fp16 via per-wave LDS transpose ----
    half_t* Pw = &Plds[w * 512];
#pragma unroll
    for (int jt = 0; jt < 2; ++jt)
#pragma unroll
      for (int r = 0; r < 4; ++r)
        Pw[(hi * 4 + r) * 32 + jt * 16 + lr] = (half_t)s[jt][r];
    half8 pf = *(const half8*)&Pw[lr * 32 + hi * 8];

    // ---- O += P V ----
#pragma unroll
    for (int g = 0; g < 8; ++g) {
      half8 vf;
#pragma unroll
      for (int i = 0; i < 8; ++i)
        vf[i] = Vlds[(hi * 8 + i) * 136 + g * 16 + lr];
      acc[g] = __builtin_amdgcn_mfma_f32_16x16x32_f16(pf, vf, acc[g], 0, 0, 0);
    }
    __syncthreads();
  }

  // ---- epilogue: O / l ----
#pragma unroll
  for (int g = 0; g < 8; ++g)
#pragma unroll
    for (int r = 0; r < 4; ++r) {
      int row = qrow + hi * 4 + r;
      int col = h * HD + g * 16 + lr;
      Ob[(size_t)row * HID + col] = (half_t)(acc[g][r] / lrow[r]);
    }
}

// ---------------- launch ----------------
extern "C" void kernel_launch(void* const* d_in, const int* in_sizes, int n_in,
                              void* d_out, int out_size, void* d_ws, size_t ws_size,
                              hipStream_t stream) {
  const float* hs = (const float*)d_in[0];
  const float* Wq = (const float*)d_in[1];
  const float* Wk = (const float*)d_in[2];
  const float* Wv = (const float*)d_in[3];
  const float* Wo = (const float*)d_in[4];
  float* out = (float*)d_out;

  char* ws = (char*)d_ws;
  half_t* Xh    = (half_t*)(ws + 0);           // 16 MB
  half_t* Wqkvh = (half_t*)(ws + 16777216);    // 48 MB [6144][4096]
  half_t* Woh   = (half_t*)(ws + 67108864);    // 32 MB
  half_t* QKV   = (half_t*)(ws + 100663296);   // 24 MB [2048][6144]
  half_t* attnh = (half_t*)(ws + 125829120);   // 16 MB [2048][4096]
  float*  cs    = (float*)(ws + 142606336);    // 1 MB cos|sin tables
  if (ws_size < 143654912ull) return;          // loud failure if ws too small

  cast_f32_f16_k<<<8192, 256, 0, stream>>>(hs, Xh, 2097152);
  cast_f32_f16_k<<<16384, 256, 0, stream>>>(Wq, Wqkvh, 4194304);
  cast_f32_f16_k<<<4096, 256, 0, stream>>>(Wk, Wqkvh + 16777216, 1048576);
  cast_f32_f16_k<<<4096, 256, 0, stream>>>(Wv, Wqkvh + 20971520, 1048576);
  cast_f32_f16_k<<<16384, 256, 0, stream>>>(Wo, Woh, 4194304);
  rope_tables_k<<<512, 256, 0, stream>>>(cs);

  gemm_bt<1><<<dim3(16, 48), 256, 0, stream>>>(Xh, Wqkvh, (void*)QKV, 2048, 6144, 4096);
  rope_apply_k<<<20480, 256, 0, stream>>>(QKV, cs);
  attn_k<<<dim3(32, 32), 256, 0, stream>>>(QKV, attnh);
  gemm_bt<0><<<dim3(16, 32), 256, 0, stream>>>(attnh, Woh, (void*)out, 2048, 4096, 4096);
}

// Round 2
// 365.041 us; speedup vs baseline: 1.5679x; 1.5679x over previous
//
#include <hip/hip_runtime.h>
#include <stdint.h>

#define T_SEQ   2048
#define HID     4096
#define NH      32
#define NKV     8
#define HD      128
#define QCOLS   6144
#define QK_SCALE 0.08838834764831845f  // 1/sqrt(128)

typedef _Float16 half_t;
typedef _Float16 half8 __attribute__((ext_vector_type(8)));
typedef _Float16 half4v __attribute__((ext_vector_type(4)));
typedef float    f32x4 __attribute__((ext_vector_type(4)));

typedef __attribute__((address_space(1))) const void cg_void;
typedef __attribute__((address_space(3))) void lds_void;

// ---------------- cast fp32 -> fp16 (vectorized) ----------------
__global__ __launch_bounds__(256) void cast_f32_f16_k(const float* __restrict__ in,
                                                      half_t* __restrict__ out, int n4) {
  int i = blockIdx.x * 256 + threadIdx.x;
  if (i >= n4) return;
  f32x4 v = *(const f32x4*)(in + (size_t)i * 4);
  half4v o;
  o[0] = (half_t)v[0]; o[1] = (half_t)v[1]; o[2] = (half_t)v[2]; o[3] = (half_t)v[3];
  *(half4v*)(out + (size_t)i * 4) = o;
}

// ---------------- RoPE cos/sin tables ----------------
__global__ __launch_bounds__(256) void rope_tables_k(float* __restrict__ cs) {
  int idx = blockIdx.x * 256 + threadIdx.x;  // 2048*64
  int t = idx >> 6, i = idx & 63;
  float inv = expf(-(float)i * 0.14391156831212787f);
  float a = (float)t * inv;
  cs[idx] = cosf(a);
  cs[131072 + idx] = sinf(a);
}

// ---------------- RoPE apply (in-place on fp16 QKV buffer) ----------------
__global__ __launch_bounds__(256) void rope_apply_k(half_t* __restrict__ QKV,
                                                    const float* __restrict__ cs) {
  int idx = blockIdx.x * 256 + threadIdx.x;  // 2048*40*64
  int i = idx & 63;
  int rem = idx >> 6;
  int head = rem % 40;
  int t = rem / 40;
  int colbase = (head < 32) ? head * HD : HID + (head - 32) * HD;
  size_t base = (size_t)t * QCOLS + colbase;
  float c = cs[t * 64 + i], s = cs[131072 + t * 64 + i];
  float x1 = (float)QKV[base + i];
  float x2 = (float)QKV[base + 64 + i];
  float o1 = x1 * c - x2 * s;
  float o2 = x1 * s + x2 * c;
  if (head < 32) { o1 *= QK_SCALE; o2 *= QK_SCALE; }
  QKV[base + i]      = (half_t)o1;
  QKV[base + 64 + i] = (half_t)o2;
}

// ---------------- V transpose: QKV V-slice [t][kh*128+d] -> Vt[kh][d][t] ----
// reads coalesced (64 lanes x 2B = 128B contiguous), writes 16B/lane strided.
__global__ __launch_bounds__(256) void transpose_v_k(const half_t* __restrict__ QKV,
                                                     half_t* __restrict__ Vt) {
  int idx = blockIdx.x * 256 + threadIdx.x;   // 8*128*256 = 262144
  int d  = idx & 127;
  int ts = (idx >> 7) & 255;
  int kh = idx >> 15;
  half8 o;
#pragma unroll
  for (int i = 0; i < 8; ++i)
    o[i] = QKV[(size_t)(ts * 8 + i) * QCOLS + HID + NKV * HD + kh * HD + d];
  *(half8*)&Vt[(size_t)kh * (HD * T_SEQ) + (size_t)d * T_SEQ + ts * 8] = o;
}

// ---------------- fp16 GEMM: C[M][N] = A[M][K] * B[N][K]^T ----------------
// 128x128 tile, BK=64, XCD-swizzled 1D grid, global_load_lds w/ pre-swizzled
// source, XOR-swizzled ds_read_b128.
template <int OUT_HALF>
__global__ __launch_bounds__(256) void gemm_bt(const half_t* __restrict__ A,
                                               const half_t* __restrict__ B,
                                               void* __restrict__ Cout,
                                               int M, int N, int K) {
  __shared__ half_t Alds[128 * 64];
  __shared__ half_t Blds[128 * 64];
  // bijective XCD swizzle (nwg % 8 == 0 for both launches)
  const int nwg = gridDim.x;
  const int q8 = nwg >> 3;
  const int bid = blockIdx.x;
  const int swz = (bid & 7) * q8 + (bid >> 3);
  const int nbm = M >> 7;
  const int row0 = (swz % nbm) * 128;
  const int col0 = (swz / nbm) * 128;
  const int tid  = threadIdx.x;
  const int lane = tid & 63;
  const int wid  = tid >> 6;
  const int wr = wid >> 1, wc = wid & 1;
  const int lr = lane & 15, hi = lane >> 4;

  f32x4 acc[4][4] = {};

  for (int k0 = 0; k0 < K; k0 += 64) {
#pragma unroll
    for (int c = 0; c < 4; ++c) {
      int idx = c * 256 + tid;
      int r = idx >> 3, s = idx & 7;
      int cc = s ^ (r & 7);
      int base = (c * 256 + wid * 64) * 8;
      __builtin_amdgcn_global_load_lds(
          (cg_void*)(A + (size_t)(row0 + r) * K + k0 + cc * 8),
          (lds_void*)(&Alds[base]), 16, 0, 0);
      __builtin_amdgcn_global_load_lds(
          (cg_void*)(B + (size_t)(col0 + r) * K + k0 + cc * 8),
          (lds_void*)(&Blds[base]), 16, 0, 0);
    }
    __syncthreads();
#pragma unroll
    for (int kk = 0; kk < 2; ++kk) {
      half8 af[4], bf[4];
#pragma unroll
      for (int mi = 0; mi < 4; ++mi) {
        int ra = wr * 64 + mi * 16 + lr;
        int slot = (kk * 4 + hi) ^ (ra & 7);
        af[mi] = *(const half8*)&Alds[ra * 64 + slot * 8];
      }
#pragma unroll
      for (int ni = 0; ni < 4; ++ni) {
        int rb = wc * 64 + ni * 16 + lr;
        int slot = (kk * 4 + hi) ^ (rb & 7);
        bf[ni] = *(const half8*)&Blds[rb * 64 + slot * 8];
      }
#pragma unroll
      for (int mi = 0; mi < 4; ++mi)
#pragma unroll
        for (int ni = 0; ni < 4; ++ni)
          acc[mi][ni] = __builtin_amdgcn_mfma_f32_16x16x32_f16(af[mi], bf[ni], acc[mi][ni], 0, 0, 0);
    }
    __syncthreads();
  }

#pragma unroll
  for (int mi = 0; mi < 4; ++mi)
#pragma unroll
    for (int ni = 0; ni < 4; ++ni)
#pragma unroll
      for (int r = 0; r < 4; ++r) {
        int row = row0 + wr * 64 + mi * 16 + hi * 4 + r;
        int col = col0 + wc * 64 + ni * 16 + lr;
        float v = acc[mi][ni][r];
        if (OUT_HALF) ((half_t*)Cout)[(size_t)row * N + col] = (half_t)v;
        else          ((float*)Cout)[(size_t)row * N + col] = v;
      }
}

// ---------------- fused causal GQA flash attention ----------------
// grid 1024 = (qb reversed x 32 heads); 4 waves, wave w owns 16 q rows.
// KVBLK=64. K staged via global_load_lds (swizzled); V read from pre-
// transposed Vt, staged via global_load_lds (swizzled) -> all b128 reads.
__global__ __launch_bounds__(256) void attn_k(const half_t* __restrict__ QKV,
                                              const half_t* __restrict__ Vt,
                                              half_t* __restrict__ Ob) {
  const int bid = blockIdx.x;
  const int qb = 31 - (bid >> 5);   // longest blocks dispatch first
  const int h  = bid & 31;
  const int kh = h >> 2;
  const int tid = threadIdx.x;
  const int lane = tid & 63;
  const int w = tid >> 6;
  const int lr = lane & 15, hi = lane >> 4;
  const int qrow = qb * 64 + w * 16;

  __shared__ half_t Klds[64 * 128];    // [kv][128] swizzled-linear
  __shared__ half_t Vlds[128 * 64];    // [d][kv]   swizzled-linear
  __shared__ half_t Plds[4 * 16 * 72]; // per-wave P, padded rows

  const half_t* Qp  = QKV + h * HD;
  const half_t* Kp  = QKV + HID + kh * HD;
  const half_t* Vtp = Vt + (size_t)kh * (HD * T_SEQ);

  half8 qf[4];
#pragma unroll
  for (int kk = 0; kk < 4; ++kk)
    qf[kk] = *(const half8*)&Qp[(size_t)(qrow + lr) * QCOLS + kk * 32 + hi * 8];

  f32x4 acc[8] = {};
  float mrow[4], lrow[4];
#pragma unroll
  for (int r = 0; r < 4; ++r) { mrow[r] = -1e30f; lrow[r] = 0.0f; }

  half_t* Pw = &Plds[w * (16 * 72)];
  const int nt = qb + 1;
  for (int t = 0; t < nt; ++t) {
    const int kv0 = t * 64;
    // ---- stage K: 64 rows x 16 slots = 1024 chunks ----
#pragma unroll
    for (int c = 0; c < 4; ++c) {
      int chunk = c * 256 + tid;
      int r = chunk >> 4, s = chunk & 15;
      int cc = (s & 8) | ((s ^ r) & 7);
      __builtin_amdgcn_global_load_lds(
          (cg_void*)(Kp + (size_t)(kv0 + r) * QCOLS + cc * 8),
          (lds_void*)(&Klds[(c * 256 + w * 64) * 8]), 16, 0, 0);
    }
    // ---- stage Vt: 128 rows x 8 slots = 1024 chunks ----
#pragma unroll
    for (int c = 0; c < 4; ++c) {
      int chunk = c * 256 + tid;
      int r = chunk >> 3, s = chunk & 7;
      int cc = (s ^ r) & 7;
      __builtin_amdgcn_global_load_lds(
          (cg_void*)(Vtp + (size_t)r * T_SEQ + kv0 + cc * 8),
          (lds_void*)(&Vlds[(c * 256 + w * 64) * 8]), 16, 0, 0);
    }
    __syncthreads();

    // ---- S = Q K^T (16 rows x 64 cols) ----
    f32x4 s[4] = {};
#pragma unroll
    for (int jt = 0; jt < 4; ++jt)
#pragma unroll
      for (int kk = 0; kk < 4; ++kk) {
        int srow = jt * 16 + lr;
        int sl = kk * 4 + hi;
        int c = (sl & 8) | ((sl ^ srow) & 7);
        half8 kf = *(const half8*)&Klds[srow * 128 + c * 8];
        s[jt] = __builtin_amdgcn_mfma_f32_16x16x32_f16(qf[kk], kf, s[jt], 0, 0, 0);
      }

    // ---- causal mask (diagonal tile only) ----
    if (t == qb) {
#pragma unroll
      for (int jt = 0; jt < 4; ++jt)
#pragma unroll
        for (int r = 0; r < 4; ++r) {
          int ig = qrow + hi * 4 + r;
          int jg = kv0 + jt * 16 + lr;
          if (jg > ig) s[jt][r] = -1e30f;
        }
    }

    // ---- online softmax ----
    float mx[4], scl[4], ls[4];
#pragma unroll
    for (int r = 0; r < 4; ++r)
      mx[r] = fmaxf(fmaxf(s[0][r], s[1][r]), fmaxf(s[2][r], s[3][r]));
#pragma unroll
    for (int off = 1; off < 16; off <<= 1)
#pragma unroll
      for (int r = 0; r < 4; ++r)
        mx[r] = fmaxf(mx[r], __shfl_xor(mx[r], off, 64));
#pragma unroll
    for (int r = 0; r < 4; ++r) {
      float mn = fmaxf(mrow[r], mx[r]);
      scl[r] = __expf(mrow[r] - mn);
      mrow[r] = mn;
      ls[r] = 0.0f;
#pragma unroll
      for (int jt = 0; jt < 4; ++jt) {
        s[jt][r] = __expf(s[jt][r] - mn);
        ls[r] += s[jt][r];
      }
    }
#pragma unroll
    for (int off = 1; off < 16; off <<= 1)
#pragma unroll
      for (int r = 0; r < 4; ++r)
        ls[r] += __shfl_xor(ls[r], off, 64);
#pragma unroll
    for (int r = 0; r < 4; ++r) lrow[r] = lrow[r] * scl[r] + ls[r];
#pragma unroll
    for (int g = 0; g < 8; ++g)
#pragma unroll
      for (int r = 0; r < 4; ++r) acc[g][r] *= scl[r];

    // ---- P -> fp16 via per-wave LDS transpose (padded, ~4-way max) ----
#pragma unroll
    for (int jt = 0; jt < 4; ++jt)
#pragma unroll
      for (int r = 0; r < 4; ++r)
        Pw[(hi * 4 + r) * 72 + jt * 16 + lr] = (half_t)s[jt][r];
    half8 pf[2];
#pragma unroll
    for (int jt = 0; jt < 2; ++jt)
      pf[jt] = *(const half8*)&Pw[lr * 72 + jt * 32 + hi * 8];

    // ---- O += P V (V^T rows from swizzled Vlds, all b128) ----
#pragma unroll
    for (int g = 0; g < 8; ++g)
#pragma unroll
      for (int jt = 0; jt < 2; ++jt) {
        int vrow = g * 16 + lr;
        int sl = jt * 4 + hi;
        int c = (sl ^ vrow) & 7;
        half8 vf = *(const half8*)&Vlds[vrow * 64 + c * 8];
        acc[g] = __builtin_amdgcn_mfma_f32_16x16x32_f16(pf[jt], vf, acc[g], 0, 0, 0);
      }
    __syncthreads();
  }

  // ---- epilogue: O / l ----
#pragma unroll
  for (int g = 0; g < 8; ++g)
#pragma unroll
    for (int r = 0; r < 4; ++r) {
      int row = qrow + hi * 4 + r;
      int col = h * HD + g * 16 + lr;
      Ob[(size_t)row * HID + col] = (half_t)(acc[g][r] / lrow[r]);
    }
}

// ---------------- launch ----------------
extern "C" void kernel_launch(void* const* d_in, const int* in_sizes, int n_in,
                              void* d_out, int out_size, void* d_ws, size_t ws_size,
                              hipStream_t stream) {
  const float* hs = (const float*)d_in[0];
  const float* Wq = (const float*)d_in[1];
  const float* Wk = (const float*)d_in[2];
  const float* Wv = (const float*)d_in[3];
  const float* Wo = (const float*)d_in[4];
  float* out = (float*)d_out;

  char* ws = (char*)d_ws;
  half_t* Xh    = (half_t*)(ws + 0);           // 16 MB (dead after gemm1)
  half_t* Vt    = (half_t*)(ws + 0);           // 4 MB, reuses Xh region
  half_t* Wqkvh = (half_t*)(ws + 16777216);    // 48 MB [6144][4096]
  half_t* Woh   = (half_t*)(ws + 67108864);    // 32 MB
  half_t* QKV   = (half_t*)(ws + 100663296);   // 24 MB [2048][6144]
  half_t* attnh = (half_t*)(ws + 125829120);   // 16 MB [2048][4096]
  float*  cs    = (float*)(ws + 142606336);    // 1 MB cos|sin tables
  if (ws_size < 143654912ull) return;

  cast_f32_f16_k<<<8192, 256, 0, stream>>>(hs, Xh, 2097152);
  cast_f32_f16_k<<<16384, 256, 0, stream>>>(Wq, Wqkvh, 4194304);
  cast_f32_f16_k<<<4096, 256, 0, stream>>>(Wk, Wqkvh + 16777216, 1048576);
  cast_f32_f16_k<<<4096, 256, 0, stream>>>(Wv, Wqkvh + 20971520, 1048576);
  cast_f32_f16_k<<<16384, 256, 0, stream>>>(Wo, Woh, 4194304);
  rope_tables_k<<<512, 256, 0, stream>>>(cs);

  gemm_bt<1><<<768, 256, 0, stream>>>(Xh, Wqkvh, (void*)QKV, 2048, 6144, 4096);
  rope_apply_k<<<20480, 256, 0, stream>>>(QKV, cs);
  transpose_v_k<<<1024, 256, 0, stream>>>(QKV, Vt);   // Xh dead now; Vt overwrites it
  attn_k<<<1024, 256, 0, stream>>>(QKV, Vt, attnh);
  gemm_bt<0><<<512, 256, 0, stream>>>(attnh, Woh, (void*)out, 2048, 4096, 4096);
}

// Round 3
// 336.040 us; speedup vs baseline: 1.7032x; 1.0863x over previous
//
#include <hip/hip_runtime.h>
#include <stdint.h>

#define T_SEQ   2048
#define HID     4096
#define NH      32
#define NKV     8
#define HD      128
#define QCOLS   6144
#define QK_SCALE 0.08838834764831845f  // 1/sqrt(128)

typedef _Float16 half_t;
typedef _Float16 half8 __attribute__((ext_vector_type(8)));
typedef _Float16 half4v __attribute__((ext_vector_type(4)));
typedef float    f32x4 __attribute__((ext_vector_type(4)));

typedef __attribute__((address_space(1))) const void cg_void;
typedef __attribute__((address_space(3))) void lds_void;

// ---------------- fused cast fp32 -> fp16 for all five inputs ----------------
__global__ __launch_bounds__(256) void cast_all_k(const float* __restrict__ X,
                                                  const float* __restrict__ Wq,
                                                  const float* __restrict__ Wk,
                                                  const float* __restrict__ Wv,
                                                  const float* __restrict__ Wo,
                                                  half_t* __restrict__ Xh,
                                                  half_t* __restrict__ Wqkvh,
                                                  half_t* __restrict__ Woh) {
  int i = blockIdx.x * 256 + threadIdx.x;   // float4 index, total 12582912
  const float* src; half_t* dst; int off;
  if (i < 2097152)      { src = X;  dst = Xh;               off = i; }
  else if (i < 6291456) { src = Wq; dst = Wqkvh;            off = i - 2097152; }
  else if (i < 7340032) { src = Wk; dst = Wqkvh + 16777216; off = i - 6291456; }
  else if (i < 8388608) { src = Wv; dst = Wqkvh + 20971520; off = i - 7340032; }
  else                  { src = Wo; dst = Woh;              off = i - 8388608; }
  f32x4 v = *(const f32x4*)(src + (size_t)off * 4);
  half4v o;
  o[0] = (half_t)v[0]; o[1] = (half_t)v[1]; o[2] = (half_t)v[2]; o[3] = (half_t)v[3];
  *(half4v*)(dst + (size_t)off * 4) = o;
}

// ---------------- RoPE cos/sin tables ----------------
__global__ __launch_bounds__(256) void rope_tables_k(float* __restrict__ cs) {
  int idx = blockIdx.x * 256 + threadIdx.x;  // 2048*64
  int t = idx >> 6, i = idx & 63;
  float inv = expf(-(float)i * 0.14391156831212787f);
  float a = (float)t * inv;
  cs[idx] = cosf(a);
  cs[131072 + idx] = sinf(a);
}

// ---------------- RoPE apply (in-place on fp16 QKV buffer) ----------------
__global__ __launch_bounds__(256) void rope_apply_k(half_t* __restrict__ QKV,
                                                    const float* __restrict__ cs) {
  int idx = blockIdx.x * 256 + threadIdx.x;  // 2048*40*64
  int i = idx & 63;
  int rem = idx >> 6;
  int head = rem % 40;
  int t = rem / 40;
  int colbase = (head < 32) ? head * HD : HID + (head - 32) * HD;
  size_t base = (size_t)t * QCOLS + colbase;
  float c = cs[t * 64 + i], s = cs[131072 + t * 64 + i];
  float x1 = (float)QKV[base + i];
  float x2 = (float)QKV[base + 64 + i];
  float o1 = x1 * c - x2 * s;
  float o2 = x1 * s + x2 * c;
  if (head < 32) { o1 *= QK_SCALE; o2 *= QK_SCALE; }
  QKV[base + i]      = (half_t)o1;
  QKV[base + 64 + i] = (half_t)o2;
}

// ---------------- V transpose: QKV V-slice [t][kh*128+d] -> Vt[kh][d][t] ----
__global__ __launch_bounds__(256) void transpose_v_k(const half_t* __restrict__ QKV,
                                                     half_t* __restrict__ Vt) {
  int idx = blockIdx.x * 256 + threadIdx.x;   // 8*128*256 = 262144
  int d  = idx & 127;
  int ts = (idx >> 7) & 255;
  int kh = idx >> 15;
  half8 o;
#pragma unroll
  for (int i = 0; i < 8; ++i)
    o[i] = QKV[(size_t)(ts * 8 + i) * QCOLS + HID + NKV * HD + kh * HD + d];
  *(half8*)&Vt[(size_t)kh * (HD * T_SEQ) + (size_t)d * T_SEQ + ts * 8] = o;
}

// ---------------- fp16 GEMM, 8-phase 256-CU-exact template ----------------
// C[M][N] = A[M][K] * B[N][K]^T.  512 thr = 8 waves (2M x 4N), BK=64,
// double-buffered LDS, per-phase {stage || ds_read || MFMA cluster} with raw
// s_barrier; one vmcnt(0)+__syncthreads per K-tile. XOR-(row&7) LDS swizzle
// (both-sides involution: pre-swizzled global source, swizzled ds_read).
template <int BM, int BN, int OUT_HALF>
__global__ __launch_bounds__(512, 2) void gemm8p_k(const half_t* __restrict__ A,
                                                   const half_t* __restrict__ Bm,
                                                   void* __restrict__ Cout,
                                                   int M, int N, int K) {
  constexpr int MF = BM / 32;   // per-wave m fragments
  constexpr int NF = BN / 64;   // per-wave n fragments
  constexpr int MH = MF / 2;    // m frags per phase
  constexpr int LA = BM / 64;   // staging loads/thread for A tile
  constexpr int LB = BN / 64;
  __shared__ half_t Al[2][BM * 64];
  __shared__ half_t Bl[2][BN * 64];

  const int nbm = M / BM;
  const int nwg = nbm * (N / BN);     // 256 for both instantiations
  const int bid = blockIdx.x;
  const int swz = (bid & 7) * (nwg >> 3) + (bid >> 3);  // bijective XCD swizzle
  const int brow = (swz % nbm) * BM;
  const int bcol = (swz / nbm) * BN;
  const int tid = threadIdx.x;
  const int lane = tid & 63, wid = tid >> 6;
  const int wr = wid >> 2, wc = wid & 3;
  const int lr = lane & 15, hi = lane >> 4;
  const int wrow = wr * (MF * 16), wcol = wc * (NF * 16);

  const half_t* Ab = A + (size_t)brow * K;
  const half_t* Bb = Bm + (size_t)bcol * K;

  f32x4 acc[MF][NF] = {};
  half8 afr[MH], bfr[NF];

#define STAGE_A(l, k0, buf) { \
    int c_ = (l) * 512 + tid; int r_ = c_ >> 3, s_ = c_ & 7; \
    __builtin_amdgcn_global_load_lds( \
      (cg_void*)(Ab + (size_t)r_ * K + (k0) + ((s_ ^ (r_ & 7)) * 8)), \
      (lds_void*)(&Al[buf][((l) * 512 + wid * 64) * 8]), 16, 0, 0); }
#define STAGE_B(l, k0, buf) { \
    int c_ = (l) * 512 + tid; int r_ = c_ >> 3, s_ = c_ & 7; \
    __builtin_amdgcn_global_load_lds( \
      (cg_void*)(Bb + (size_t)r_ * K + (k0) + ((s_ ^ (r_ & 7)) * 8)), \
      (lds_void*)(&Bl[buf][((l) * 512 + wid * 64) * 8]), 16, 0, 0); }
#define RD_A(i, mh, kk, buf) { \
    int row_ = wrow + ((mh) * MH + (i)) * 16 + lr; int ks_ = (kk) * 4 + hi; \
    afr[i] = *(const half8*)&Al[buf][row_ * 64 + ((ks_ ^ (row_ & 7)) * 8)]; }
#define RD_B(n, kk, buf) { \
    int row_ = wcol + (n) * 16 + lr; int ks_ = (kk) * 4 + hi; \
    bfr[n] = *(const half8*)&Bl[buf][row_ * 64 + ((ks_ ^ (row_ & 7)) * 8)]; }
#define MFMA_PH(mh) { \
    __builtin_amdgcn_s_setprio(1); \
    _Pragma("unroll") for (int i_ = 0; i_ < MH; ++i_) \
      _Pragma("unroll") for (int n_ = 0; n_ < NF; ++n_) \
        acc[(mh) * MH + i_][n_] = __builtin_amdgcn_mfma_f32_16x16x32_f16( \
            afr[i_], bfr[n_], acc[(mh) * MH + i_][n_], 0, 0, 0); \
    __builtin_amdgcn_s_setprio(0); }

#define DO_TILE(T, BUF) { \
    const int kn_ = ((T) + 1) * 64; const bool pf_ = ((T) + 1) < NT; \
    /* phase 0: mh0,kk0 ; stage next-A */ \
    if (pf_) { _Pragma("unroll") for (int l_ = 0; l_ < LA; ++l_) STAGE_A(l_, kn_, (BUF) ^ 1); } \
    _Pragma("unroll") for (int n_ = 0; n_ < NF; ++n_) RD_B(n_, 0, BUF); \
    _Pragma("unroll") for (int i_ = 0; i_ < MH; ++i_) RD_A(i_, 0, 0, BUF); \
    MFMA_PH(0); \
    __builtin_amdgcn_s_barrier(); __builtin_amdgcn_sched_barrier(0); \
    /* phase 1: mh1,kk0 (reuse bfr) ; stage next-B */ \
    if (pf_) { _Pragma("unroll") for (int l_ = 0; l_ < LB; ++l_) STAGE_B(l_, kn_, (BUF) ^ 1); } \
    _Pragma("unroll") for (int i_ = 0; i_ < MH; ++i_) RD_A(i_, 1, 0, BUF); \
    MFMA_PH(1); \
    __builtin_amdgcn_s_barrier(); __builtin_amdgcn_sched_barrier(0); \
    /* phase 2: mh1,kk1 */ \
    _Pragma("unroll") for (int n_ = 0; n_ < NF; ++n_) RD_B(n_, 1, BUF); \
    _Pragma("unroll") for (int i_ = 0; i_ < MH; ++i_) RD_A(i_, 1, 1, BUF); \
    MFMA_PH(1); \
    __builtin_amdgcn_s_barrier(); __builtin_amdgcn_sched_barrier(0); \
    /* phase 3: mh0,kk1 (reuse bfr) */ \
    _Pragma("unroll") for (int i_ = 0; i_ < MH; ++i_) RD_A(i_, 0, 1, BUF); \
    MFMA_PH(0); \
    asm volatile("s_waitcnt vmcnt(0)" ::: "memory"); \
    __syncthreads(); }

  const int NT = K / 64;
  // prologue: stage tile 0 into buf0, drain, sync
#pragma unroll
  for (int l_ = 0; l_ < LA; ++l_) STAGE_A(l_, 0, 0);
#pragma unroll
  for (int l_ = 0; l_ < LB; ++l_) STAGE_B(l_, 0, 0);
  asm volatile("s_waitcnt vmcnt(0)" ::: "memory");
  __syncthreads();

  for (int t = 0; t < NT; t += 2) {
    DO_TILE(t, 0);
    DO_TILE(t + 1, 1);
  }

#undef STAGE_A
#undef STAGE_B
#undef RD_A
#undef RD_B
#undef MFMA_PH
#undef DO_TILE

#pragma unroll
  for (int m = 0; m < MF; ++m)
#pragma unroll
    for (int n = 0; n < NF; ++n)
#pragma unroll
      for (int r = 0; r < 4; ++r) {
        int row = brow + wrow + m * 16 + hi * 4 + r;
        int col = bcol + wcol + n * 16 + lr;
        float v = acc[m][n][r];
        if (OUT_HALF) ((half_t*)Cout)[(size_t)row * N + col] = (half_t)v;
        else          ((float*)Cout)[(size_t)row * N + col] = v;
      }
}

// ---------------- fused causal GQA flash attention (unchanged) ----------------
__global__ __launch_bounds__(256) void attn_k(const half_t* __restrict__ QKV,
                                              const half_t* __restrict__ Vt,
                                              half_t* __restrict__ Ob) {
  const int bid = blockIdx.x;
  const int qb = 31 - (bid >> 5);
  const int h  = bid & 31;
  const int kh = h >> 2;
  const int tid = threadIdx.x;
  const int lane = tid & 63;
  const int w = tid >> 6;
  const int lr = lane & 15, hi = lane >> 4;
  const int qrow = qb * 64 + w * 16;

  __shared__ half_t Klds[64 * 128];
  __shared__ half_t Vlds[128 * 64];
  __shared__ half_t Plds[4 * 16 * 72];

  const half_t* Qp  = QKV + h * HD;
  const half_t* Kp  = QKV + HID + kh * HD;
  const half_t* Vtp = Vt + (size_t)kh * (HD * T_SEQ);

  half8 qf[4];
#pragma unroll
  for (int kk = 0; kk < 4; ++kk)
    qf[kk] = *(const half8*)&Qp[(size_t)(qrow + lr) * QCOLS + kk * 32 + hi * 8];

  f32x4 acc[8] = {};
  float mrow[4], lrow[4];
#pragma unroll
  for (int r = 0; r < 4; ++r) { mrow[r] = -1e30f; lrow[r] = 0.0f; }

  half_t* Pw = &Plds[w * (16 * 72)];
  const int nt = qb + 1;
  for (int t = 0; t < nt; ++t) {
    const int kv0 = t * 64;
#pragma unroll
    for (int c = 0; c < 4; ++c) {
      int chunk = c * 256 + tid;
      int r = chunk >> 4, s = chunk & 15;
      int cc = (s & 8) | ((s ^ r) & 7);
      __builtin_amdgcn_global_load_lds(
          (cg_void*)(Kp + (size_t)(kv0 + r) * QCOLS + cc * 8),
          (lds_void*)(&Klds[(c * 256 + w * 64) * 8]), 16, 0, 0);
    }
#pragma unroll
    for (int c = 0; c < 4; ++c) {
      int chunk = c * 256 + tid;
      int r = chunk >> 3, s = chunk & 7;
      int cc = (s ^ r) & 7;
      __builtin_amdgcn_global_load_lds(
          (cg_void*)(Vtp + (size_t)r * T_SEQ + kv0 + cc * 8),
          (lds_void*)(&Vlds[(c * 256 + w * 64) * 8]), 16, 0, 0);
    }
    __syncthreads();

    f32x4 s[4] = {};
#pragma unroll
    for (int jt = 0; jt < 4; ++jt)
#pragma unroll
      for (int kk = 0; kk < 4; ++kk) {
        int srow = jt * 16 + lr;
        int sl = kk * 4 + hi;
        int c = (sl & 8) | ((sl ^ srow) & 7);
        half8 kf = *(const half8*)&Klds[srow * 128 + c * 8];
        s[jt] = __builtin_amdgcn_mfma_f32_16x16x32_f16(qf[kk], kf, s[jt], 0, 0, 0);
      }

    if (t == qb) {
#pragma unroll
      for (int jt = 0; jt < 4; ++jt)
#pragma unroll
        for (int r = 0; r < 4; ++r) {
          int ig = qrow + hi * 4 + r;
          int jg = kv0 + jt * 16 + lr;
          if (jg > ig) s[jt][r] = -1e30f;
        }
    }

    float mx[4], scl[4], ls[4];
#pragma unroll
    for (int r = 0; r < 4; ++r)
      mx[r] = fmaxf(fmaxf(s[0][r], s[1][r]), fmaxf(s[2][r], s[3][r]));
#pragma unroll
    for (int off = 1; off < 16; off <<= 1)
#pragma unroll
      for (int r = 0; r < 4; ++r)
        mx[r] = fmaxf(mx[r], __shfl_xor(mx[r], off, 64));
#pragma unroll
    for (int r = 0; r < 4; ++r) {
      float mn = fmaxf(mrow[r], mx[r]);
      scl[r] = __expf(mrow[r] - mn);
      mrow[r] = mn;
      ls[r] = 0.0f;
#pragma unroll
      for (int jt = 0; jt < 4; ++jt) {
        s[jt][r] = __expf(s[jt][r] - mn);
        ls[r] += s[jt][r];
      }
    }
#pragma unroll
    for (int off = 1; off < 16; off <<= 1)
#pragma unroll
      for (int r = 0; r < 4; ++r)
        ls[r] += __shfl_xor(ls[r], off, 64);
#pragma unroll
    for (int r = 0; r < 4; ++r) lrow[r] = lrow[r] * scl[r] + ls[r];
#pragma unroll
    for (int g = 0; g < 8; ++g)
#pragma unroll
      for (int r = 0; r < 4; ++r) acc[g][r] *= scl[r];

#pragma unroll
    for (int jt = 0; jt < 4; ++jt)
#pragma unroll
      for (int r = 0; r < 4; ++r)
        Pw[(hi * 4 + r) * 72 + jt * 16 + lr] = (half_t)s[jt][r];
    half8 pf[2];
#pragma unroll
    for (int jt = 0; jt < 2; ++jt)
      pf[jt] = *(const half8*)&Pw[lr * 72 + jt * 32 + hi * 8];

#pragma unroll
    for (int g = 0; g < 8; ++g)
#pragma unroll
      for (int jt = 0; jt < 2; ++jt) {
        int vrow = g * 16 + lr;
        int sl = jt * 4 + hi;
        int c = (sl ^ vrow) & 7;
        half8 vf = *(const half8*)&Vlds[vrow * 64 + c * 8];
        acc[g] = __builtin_amdgcn_mfma_f32_16x16x32_f16(pf[jt], vf, acc[g], 0, 0, 0);
      }
    __syncthreads();
  }

#pragma unroll
  for (int g = 0; g < 8; ++g)
#pragma unroll
    for (int r = 0; r < 4; ++r) {
      int row = qrow + hi * 4 + r;
      int col = h * HD + g * 16 + lr;
      Ob[(size_t)row * HID + col] = (half_t)(acc[g][r] / lrow[r]);
    }
}

// ---------------- launch ----------------
extern "C" void kernel_launch(void* const* d_in, const int* in_sizes, int n_in,
                              void* d_out, int out_size, void* d_ws, size_t ws_size,
                              hipStream_t stream) {
  const float* hs = (const float*)d_in[0];
  const float* Wq = (const float*)d_in[1];
  const float* Wk = (const float*)d_in[2];
  const float* Wv = (const float*)d_in[3];
  const float* Wo = (const float*)d_in[4];
  float* out = (float*)d_out;

  char* ws = (char*)d_ws;
  half_t* Xh    = (half_t*)(ws + 0);           // 16 MB (dead after gemm1)
  half_t* Vt    = (half_t*)(ws + 0);           // 4 MB, reuses Xh region
  half_t* Wqkvh = (half_t*)(ws + 16777216);    // 48 MB [6144][4096]
  half_t* Woh   = (half_t*)(ws + 67108864);    // 32 MB
  half_t* QKV   = (half_t*)(ws + 100663296);   // 24 MB [2048][6144]
  half_t* attnh = (half_t*)(ws + 125829120);   // 16 MB [2048][4096]
  float*  cs    = (float*)(ws + 142606336);    // 1 MB cos|sin tables
  if (ws_size < 143654912ull) return;

  cast_all_k<<<49152, 256, 0, stream>>>(hs, Wq, Wk, Wv, Wo, Xh, Wqkvh, Woh);
  rope_tables_k<<<512, 256, 0, stream>>>(cs);

  gemm8p_k<256, 192, 1><<<256, 512, 0, stream>>>(Xh, Wqkvh, (void*)QKV, 2048, 6144, 4096);
  rope_apply_k<<<20480, 256, 0, stream>>>(QKV, cs);
  transpose_v_k<<<1024, 256, 0, stream>>>(QKV, Vt);
  attn_k<<<1024, 256, 0, stream>>>(QKV, Vt, attnh);
  gemm8p_k<128, 256, 0><<<256, 512, 0, stream>>>(attnh, Woh, (void*)out, 2048, 4096, 4096);
}